// Round 10
// baseline (193.798 us; speedup 1.0000x reference)
//
#include <hip/hip_runtime.h>
#include <hip/hip_bf16.h>
#include <math.h>

// Problem constants
#define BATCH 2
#define SLEN  2048
#define DIN   1024
#define DMODEL 1024
#define NHEAD 16
#define HD    64
#define E3    3072   // 3*DMODEL, row width of qkv

typedef unsigned short us;
typedef _Float16 f16;
typedef __attribute__((ext_vector_type(8))) _Float16 f16x8;
typedef __attribute__((ext_vector_type(8))) unsigned short us8;
typedef __attribute__((ext_vector_type(4))) unsigned short us4;
typedef __attribute__((ext_vector_type(4))) float f32x4;
typedef __attribute__((ext_vector_type(16))) float f32x16;
typedef __attribute__((ext_vector_type(4))) unsigned int u32x4;

// 0.125 (1/sqrt(HD)) * log2(e): folded into Q at qkv-GEMM epilogue so the
// attention softmax is a bare exp2 of the raw MFMA score.
#define QSCALE 0.18033688011112042f

__device__ __forceinline__ us f16bits(float x) {
    const f16 h = (f16)x;
    return __builtin_bit_cast(us, h);
}

__device__ __forceinline__ unsigned int pkrtz(float a, float b) {
    return __builtin_bit_cast(unsigned int, __builtin_amdgcn_cvt_pkrtz(a, b));
}

// v_permlane32_swap_b32: a' = {a.lo, b.lo}, b' = {a.hi, b.hi}
__device__ __forceinline__ void plswap(unsigned int& a, unsigned int& b) {
    asm volatile("v_permlane32_swap_b32 %0, %1" : "+v"(a), "+v"(b));
}

__device__ __forceinline__ void barrier_raw() {
    asm volatile("s_barrier" ::: "memory");
}

// async 16B global->LDS (lane i deposits at ldsbase + i*16)
#define GLL16(g, l)                                                                     \
    __builtin_amdgcn_global_load_lds((const __attribute__((address_space(1))) unsigned int*)(g), \
                                     (__attribute__((address_space(3))) unsigned int*)(l), 16, 0, 0)

// ---------------- fp32 -> fp16 for x, w_qkv, w_o in one launch ----------------
__global__ __launch_bounds__(256) void cvt3_f16(
    const float* __restrict__ x, us* __restrict__ ox, int nx,
    const float* __restrict__ wq, us* __restrict__ owq, int nq,
    const float* __restrict__ wo, us* __restrict__ owo)
{
    int i = (blockIdx.x * 256 + threadIdx.x) * 8;
    const float* s;
    us* o;
    if (i < nx)           { s = x;  o = ox; }
    else if (i < nx + nq) { s = wq; o = owq; i -= nx; }
    else                  { s = wo; o = owo; i -= nx + nq; }
    const float4 f0 = *(const float4*)&s[i];
    const float4 f1 = *(const float4*)&s[i + 4];
    const float v[8] = {f0.x, f0.y, f0.z, f0.w, f1.x, f1.y, f1.z, f1.w};
    us8 h;
#pragma unroll
    for (int j = 0; j < 8; ++j) h[j] = f16bits(v[j]);
    *(us8*)&o[i] = h;
}

// ---------------- 256x256 8-wave counted-vmcnt MFMA GEMM (qkv; unchanged R9) ----
#define G2BK 64

template <bool QKV_OUT>
__global__ __launch_bounds__(512, 1) void gemm256_f16(
    const us* __restrict__ Am, const us* __restrict__ Bm,
    const float* __restrict__ bias, void* __restrict__ Cout,
    int M, int N, int K)
{
    __shared__ __align__(16) us ldsA[2 * 256 * 64];   // 64 KB
    __shared__ __align__(16) us ldsB[2 * 256 * 64];   // 64 KB

    const int t    = threadIdx.x;
    const int lane = t & 63;
    const int w    = t >> 6;        // wave 0..7
    const int ml   = lane & 15;
    const int quad = lane >> 4;
    const int msk  = ml & 7;
    const int wm   = w >> 2;        // 0..1 (row half)
    const int wn   = w & 3;         // 0..3 (col quarter)
    const int GNT  = K / G2BK;      // 16

    // XCD-aware bijective block swizzle (nwg = 192, %8 == 0)
    const int nbx = N >> 8;
    const int nwg = (M >> 8) * nbx;
    int wg = blockIdx.y * nbx + blockIdx.x;
    wg = (wg & 7) * (nwg >> 3) + (wg >> 3);
    const int m0 = (wg / nbx) * 256;
    const int n0 = (wg % nbx) * 256;

    const int r8  = lane >> 3;
    const int xsw = ((lane & 7) ^ r8) * 8;
    const us* pA = Am + (size_t)(m0 + w * 32 + r8) * K + xsw;
    const us* pB = Bm + (size_t)(n0 + w * 32 + r8) * K + xsw;

#define STG_A(d, kk) do { _Pragma("unroll") for (int g = 0; g < 4; ++g) \
    GLL16(pA + (size_t)(8 * g) * K + (kk), &ldsA[(d) * 16384 + w * 2048 + g * 512]); } while (0)
#define STG_B(d, kk) do { _Pragma("unroll") for (int g = 0; g < 4; ++g) \
    GLL16(pB + (size_t)(8 * g) * K + (kk), &ldsB[(d) * 16384 + w * 2048 + g * 512]); } while (0)

#define LDA(d, mi, ks) __builtin_bit_cast(f16x8, *(const us8*)&ldsA[(d) * 16384 + (wm * 128 + (mi) * 16 + ml) * 64 + (((quad ^ msk) ^ ((ks) << 2)) * 8)])
#define LDB(d, nj, ks) __builtin_bit_cast(f16x8, *(const us8*)&ldsB[(d) * 16384 + (wn * 64 + (nj) * 16 + ml) * 64 + (((quad ^ msk) ^ ((ks) << 2)) * 8)])

    f32x4 acc[8][4];
#pragma unroll
    for (int i = 0; i < 8; ++i)
#pragma unroll
        for (int j = 0; j < 4; ++j) {
            acc[i][j][0] = 0.f; acc[i][j][1] = 0.f; acc[i][j][2] = 0.f; acc[i][j][3] = 0.f;
        }

    STG_A(0, 0); STG_B(0, 0);
    STG_B(1, G2BK);
    asm volatile("s_waitcnt vmcnt(4)" ::: "memory");
    barrier_raw();

    for (int tt = 0; tt < GNT; ++tt) {
        const int d = tt & 1, e = d ^ 1;

        if (tt + 1 < GNT) STG_A(e, (tt + 1) * G2BK);
        f16x8 bf[2][4];
#pragma unroll
        for (int ks = 0; ks < 2; ++ks)
#pragma unroll
            for (int nj = 0; nj < 4; ++nj)
                bf[ks][nj] = LDB(d, nj, ks);
        f16x8 af[4][2];
#pragma unroll
        for (int mi = 0; mi < 4; ++mi) {
            af[mi][0] = LDA(d, mi, 0);
            af[mi][1] = LDA(d, mi, 1);
        }
        __builtin_amdgcn_s_setprio(1);
#pragma unroll
        for (int ks = 0; ks < 2; ++ks)
#pragma unroll
            for (int nj = 0; nj < 4; ++nj)
#pragma unroll
                for (int mi = 0; mi < 4; ++mi)
                    acc[mi][nj] = __builtin_amdgcn_mfma_f32_16x16x32_f16(af[mi][ks], bf[ks][nj], acc[mi][nj], 0, 0, 0);
        __builtin_amdgcn_s_setprio(0);
        barrier_raw();

        if (tt + 2 < GNT) STG_B(d, (tt + 2) * G2BK);
#pragma unroll
        for (int mi = 0; mi < 4; ++mi) {
            af[mi][0] = LDA(d, mi + 4, 0);
            af[mi][1] = LDA(d, mi + 4, 1);
        }
        __builtin_amdgcn_s_setprio(1);
#pragma unroll
        for (int ks = 0; ks < 2; ++ks)
#pragma unroll
            for (int nj = 0; nj < 4; ++nj)
#pragma unroll
                for (int mi = 0; mi < 4; ++mi)
                    acc[mi + 4][nj] = __builtin_amdgcn_mfma_f32_16x16x32_f16(af[mi][ks], bf[ks][nj], acc[mi + 4][nj], 0, 0, 0);
        __builtin_amdgcn_s_setprio(0);

        if (tt + 2 < GNT)      asm volatile("s_waitcnt vmcnt(4)" ::: "memory");
        else if (tt + 1 < GNT) asm volatile("s_waitcnt vmcnt(0)" ::: "memory");
        barrier_raw();
    }

    float bj[4], cs[4];
#pragma unroll
    for (int nj = 0; nj < 4; ++nj) {
        const int col = n0 + wn * 64 + nj * 16 + ml;
        bj[nj] = bias[col];
        cs[nj] = (QKV_OUT && (col % 192) < 64) ? QSCALE : 1.0f;
    }
#pragma unroll
    for (int mi = 0; mi < 8; ++mi) {
#pragma unroll
        for (int r = 0; r < 4; ++r) {
            const size_t rowoff = (size_t)(m0 + wm * 128 + mi * 16 + quad * 4 + r) * N;
#pragma unroll
            for (int nj = 0; nj < 4; ++nj) {
                const int col = n0 + wn * 64 + nj * 16 + ml;
                const float v = (acc[mi][nj][r] + bj[nj]) * cs[nj];
                if (QKV_OUT) ((us*)Cout)[rowoff + col] = f16bits(v);
                else         ((float*)Cout)[rowoff + col] = v;
            }
        }
    }
#undef STG_A
#undef STG_B
#undef LDA
#undef LDB
}

// ---------------- 128xBN double-buffered counted-vmcnt MFMA GEMM (out; R3) ----
#define GBK 64
#define GNT (DIN / GBK)   // 16

template <int BN, bool QKV_OUT>
__global__ __launch_bounds__(256) void gemm_db(
    const us* __restrict__ Am, const us* __restrict__ Bm,
    const float* __restrict__ bias, void* __restrict__ Cout,
    int M, int N, int K)
{
    constexpr int NJ  = BN / 32;
    constexpr int BGL = BN / 32;
    __shared__ __align__(16) us ldsA[2 * 128 * 64];
    __shared__ __align__(16) us ldsB[2 * BN * 64];

    const int t    = threadIdx.x;
    const int lane = t & 63;
    const int w    = t >> 6;
    const int ml   = lane & 15;
    const int quad = lane >> 4;
    const int msk  = ml & 7;
    const int wm   = w >> 1;
    const int wn   = w & 1;

    const int nbx = N / BN;
    const int nwg = (M >> 7) * nbx;
    int wg = blockIdx.y * nbx + blockIdx.x;
    wg = (wg & 7) * (nwg >> 3) + (wg >> 3);
    const int m0 = (wg / nbx) * 128;
    const int n0 = (wg % nbx) * BN;

    const int r8  = lane >> 3;
    const int xsw = ((lane & 7) ^ r8) * 8;
    const us* pA = Am + (size_t)(m0 + w * 32 + r8) * K + xsw;
    const int brow = (BN == 128) ? w * 32 : w * 16;
    const us* pB = Bm + (size_t)(n0 + brow + r8) * K + xsw;

#define STG_A(d, kk) do { _Pragma("unroll") for (int g = 0; g < 4; ++g) \
    GLL16(pA + (size_t)(8 * g) * K + (kk), &ldsA[(d) * 8192 + w * 2048 + g * 512]); } while (0)
#define STG_B(d, kk) do { _Pragma("unroll") for (int g = 0; g < BGL; ++g) \
    GLL16(pB + (size_t)(8 * g) * K + (kk), &ldsB[(d) * (BN * 64) + brow * 64 + g * 512]); } while (0)

#define LDA(d, mi, ks) __builtin_bit_cast(f16x8, *(const us8*)&ldsA[(d) * 8192 + (wm * 64 + (mi) * 16 + ml) * 64 + (((quad ^ msk) ^ ((ks) << 2)) * 8)])
#define LDB(d, nj, ks) __builtin_bit_cast(f16x8, *(const us8*)&ldsB[(d) * (BN * 64) + (wn * (BN / 2) + (nj) * 16 + ml) * 64 + (((quad ^ msk) ^ ((ks) << 2)) * 8)])

#define WAIT_BGL() do { if constexpr (BN == 128) asm volatile("s_waitcnt vmcnt(4)" ::: "memory"); \
                        else                     asm volatile("s_waitcnt vmcnt(2)" ::: "memory"); } while (0)

    f32x4 acc[4][NJ];
#pragma unroll
    for (int i = 0; i < 4; ++i)
#pragma unroll
        for (int j = 0; j < NJ; ++j) {
            acc[i][j][0] = 0.f; acc[i][j][1] = 0.f; acc[i][j][2] = 0.f; acc[i][j][3] = 0.f;
        }

    STG_A(0, 0); STG_B(0, 0);
    STG_B(1, GBK);
    WAIT_BGL();
    barrier_raw();

    for (int tt = 0; tt < GNT; ++tt) {
        const int d = tt & 1, e = d ^ 1;

        if (tt + 1 < GNT) STG_A(e, (tt + 1) * GBK);
        f16x8 bf[2][NJ];
#pragma unroll
        for (int ks = 0; ks < 2; ++ks)
#pragma unroll
            for (int nj = 0; nj < NJ; ++nj)
                bf[ks][nj] = LDB(d, nj, ks);
        f16x8 a0[2][2];
#pragma unroll
        for (int mi = 0; mi < 2; ++mi) {
            a0[mi][0] = LDA(d, mi, 0);
            a0[mi][1] = LDA(d, mi, 1);
        }
        __builtin_amdgcn_s_setprio(1);
#pragma unroll
        for (int ks = 0; ks < 2; ++ks)
#pragma unroll
            for (int nj = 0; nj < NJ; ++nj)
#pragma unroll
                for (int mi = 0; mi < 2; ++mi)
                    acc[mi][nj] = __builtin_amdgcn_mfma_f32_16x16x32_f16(a0[mi][ks], bf[ks][nj], acc[mi][nj], 0, 0, 0);
        __builtin_amdgcn_s_setprio(0);
        barrier_raw();

        if (tt + 2 < GNT) STG_B(d, (tt + 2) * GBK);
        f16x8 a1[2][2];
#pragma unroll
        for (int mi = 0; mi < 2; ++mi) {
            a1[mi][0] = LDA(d, mi + 2, 0);
            a1[mi][1] = LDA(d, mi + 2, 1);
        }
        __builtin_amdgcn_s_setprio(1);
#pragma unroll
        for (int ks = 0; ks < 2; ++ks)
#pragma unroll
            for (int nj = 0; nj < NJ; ++nj)
#pragma unroll
                for (int mi = 0; mi < 2; ++mi)
                    acc[mi + 2][nj] = __builtin_amdgcn_mfma_f32_16x16x32_f16(a1[mi][ks], bf[ks][nj], acc[mi + 2][nj], 0, 0, 0);
        __builtin_amdgcn_s_setprio(0);

        if (tt + 2 < GNT)      WAIT_BGL();
        else if (tt + 1 < GNT) asm volatile("s_waitcnt vmcnt(0)" ::: "memory");
        barrier_raw();
    }

    float bj[NJ], cs[NJ];
#pragma unroll
    for (int nj = 0; nj < NJ; ++nj) {
        const int col = n0 + wn * (BN / 2) + nj * 16 + ml;
        bj[nj] = bias[col];
        cs[nj] = (QKV_OUT && (col % 192) < 64) ? QSCALE : 1.0f;
    }
#pragma unroll
    for (int mi = 0; mi < 4; ++mi) {
#pragma unroll
        for (int r = 0; r < 4; ++r) {
            const size_t rowoff = (size_t)(m0 + wm * 64 + mi * 16 + quad * 4 + r) * N;
#pragma unroll
            for (int nj = 0; nj < NJ; ++nj) {
                const int col = n0 + wn * (BN / 2) + nj * 16 + ml;
                const float v = (acc[mi][nj][r] + bj[nj]) * cs[nj];
                if (QKV_OUT) ((us*)Cout)[rowoff + col] = f16bits(v);
                else         ((float*)Cout)[rowoff + col] = v;
            }
        }
    }
#undef STG_A
#undef STG_B
#undef LDA
#undef LDB
#undef WAIT_BGL
}

// ---------------- MFMA flash attention, split across TWO dispatches ----------------
// Each dispatch: 256-thr blocks (4 waves), grid 512, LDS 36.9 KB -> 4 blocks/CU
// (16 waves/CU; same TLP as the 8-wave version but 4-wave barriers and 4
// independent blocks/CU). Block handles 128 q x 1024 keys (16 chunks starting
// at cbase). Same verified R8 chunk loop: K+V dbuf, ONE barrier/chunk, T12
// in-register P, Q-overlay prologue, coalesced reg-staged K/V.
// FIRST: writes unnormalized O (f32) + l to workspace. SECOND: adds its own
// partials (exact: bare-exp2 sums add), normalizes, stores vals fp16.
// Side effect: halves attn dispatch duration so the GEMMs surface in top-5.
#define ABQ 128
#define ACH 64
#define CHN 16              // chunks per dispatch (1024 keys)
#define LQA 72              // LDS row stride in fp16 elems

template <bool FIRST>
__global__ __launch_bounds__(256, 4) void attn_half(
    const us* __restrict__ qkvh, us* __restrict__ vals,
    float* __restrict__ Opart, float* __restrict__ lpart, int cbase)
{
    // [Kb0 4608 | Kb1 4608 | Vb0 4608 | Vb1 4608] us = 36864 B
    __shared__ __align__(16) us smem[18432];

    const int t    = threadIdx.x;
    const int lane = t & 63;
    const int w    = t >> 6;        // wave 0..3 (owns q rows w*32..w*32+31)
    const int m32  = lane & 31;
    const int half = lane >> 5;

    // XCD-owning decomposition: xcd = wg&7; bh = ((wg>>7)<<3)|xcd; qi = (wg>>3)&15
    const int wg  = blockIdx.x;
    const int s9  = wg >> 3;
    const int bh  = ((s9 >> 4) << 3) | (wg & 7);
    const int b   = bh >> 4;
    const int h   = bh & 15;
    const int q0  = (s9 & 15) * ABQ;

    const size_t base = (size_t)b * SLEN * E3;
    const int qoff = h * 192;

    // staging maps (256 threads cover the whole 64-key chunk)
    const int krA = t >> 2;           // K: key 0..63, 16 dims/thread (coalesced)
    const int ksA = (t & 3) * 16;
    const int k2  = t & 31;           // V: key PAIR (2*k2, 2*k2+1)
    const int d0v = (t >> 5) * 8;     // V: 8 dims/thread (8 groups x 8 = 64)

    us* const Kb0 = smem;
    us* const Kb1 = smem + 4608;
    us* const Vb0 = smem + 9216;
    us* const Vb1 = smem + 13824;

    us8 kk0, kk1, vv0, vv1;
#define LOADKV(cgi) do { \
    const us* gK = &qkvh[base + (size_t)((cgi) * ACH + krA) * E3 + qoff + 64 + ksA]; \
    kk0 = *(const us8*)gK; kk1 = *(const us8*)(gK + 8); \
    const us* gV = &qkvh[base + (size_t)((cgi) * ACH + 2 * k2) * E3 + qoff + 128 + d0v]; \
    vv0 = *(const us8*)gV; vv1 = *(const us8*)(gV + E3); } while (0)

    // ---- prologue ----
    LOADKV(cbase);                    // K(0),V(0) -> regs, issued before Q staging
    {   // stage Q (128 q x 64 d) into the Kb region: 32 elems/thread
        const int row = t >> 1;
        const int c0q = (t & 1) * 32;
        const us* g = &qkvh[base + (size_t)(q0 + row) * E3 + qoff + c0q];
        *(us8*)&smem[row * LQA + c0q]      = *(const us8*)g;
        *(us8*)&smem[row * LQA + c0q + 8]  = *(const us8*)(g + 8);
        *(us8*)&smem[row * LQA + c0q + 16] = *(const us8*)(g + 16);
        *(us8*)&smem[row * LQA + c0q + 24] = *(const us8*)(g + 24);
    }
    __syncthreads();                  // Q visible

    f16x8 aq[4];                      // Q B-frags: B[k=dim][n=q], q = w*32+m32
#pragma unroll
    for (int s = 0; s < 4; ++s)
        aq[s] = __builtin_bit_cast(f16x8, *(const us8*)&smem[(w * 32 + m32) * LQA + half * 8 + 16 * s]);
    __syncthreads();                  // aq reads retired before K(0) overwrites Q

    *(us8*)&Kb0[krA * LQA + ksA]     = kk0;
    *(us8*)&Kb0[krA * LQA + ksA + 8] = kk1;
#pragma unroll
    for (int j = 0; j < 8; ++j) {
        const unsigned int pv = (unsigned int)vv0[j] | ((unsigned int)vv1[j] << 16);
        *(unsigned int*)&Vb0[(d0v + j) * LQA + 2 * k2] = pv;
    }
    LOADKV(cbase + 1);
    __syncthreads();                  // K(0)/V(0) visible

    f32x16 O[2];
#pragma unroll
    for (int dt = 0; dt < 2; ++dt)
#pragma unroll
        for (int r = 0; r < 16; ++r) O[dt][r] = 0.f;
    float lp[2] = {0.f, 0.f};

    for (int c = 0; c < CHN; ++c) {
        us* const Krd = (c & 1) ? Kb1 : Kb0;
        us* const Vrd = (c & 1) ? Vb1 : Vb0;
        us* const Kwr = (c & 1) ? Kb0 : Kb1;
        us* const Vwr = (c & 1) ? Vb0 : Vb1;

        // write K(c+1),V(c+1) -> buf e (readers retired at last barrier)
        if (c + 1 < CHN) {
            *(us8*)&Kwr[krA * LQA + ksA]     = kk0;
            *(us8*)&Kwr[krA * LQA + ksA + 8] = kk1;
#pragma unroll
            for (int j = 0; j < 8; ++j) {
                const unsigned int pv = (unsigned int)vv0[j] | ((unsigned int)vv1[j] << 16);
                *(unsigned int*)&Vwr[(d0v + j) * LQA + 2 * k2] = pv;
            }
        }
        if (c + 2 < CHN) LOADKV(cbase + c + 2);

        // S^T = K.Q^T; exp2; T12 pack (scoped halves of 8)
        f16x8 pf[4];
#pragma unroll
        for (int kt = 0; kt < 2; ++kt) {
            f32x16 z;
#pragma unroll
            for (int r = 0; r < 16; ++r) z[r] = 0.f;
            __builtin_amdgcn_s_setprio(1);
#pragma unroll
            for (int s = 0; s < 4; ++s) {
                const f16x8 ak = __builtin_bit_cast(f16x8, *(const us8*)&Krd[(kt * 32 + m32) * LQA + half * 8 + 16 * s]);
                z = __builtin_amdgcn_mfma_f32_32x32x16_f16(ak, aq[s], z, 0, 0, 0);
            }
            __builtin_amdgcn_s_setprio(0);
            {
                float p[8];
#pragma unroll
                for (int r = 0; r < 8; ++r) {
                    p[r] = __builtin_amdgcn_exp2f(z[r]);
                    lp[r & 1] += p[r];
                }
                unsigned int a0 = pkrtz(p[0], p[1]), a1 = pkrtz(p[2], p[3]);
                unsigned int b0 = pkrtz(p[4], p[5]), b1 = pkrtz(p[6], p[7]);
                plswap(a0, b0); plswap(a1, b1);
                pf[2 * kt] = __builtin_bit_cast(f16x8, (u32x4){a0, a1, b0, b1});
            }
            {
                float p[8];
#pragma unroll
                for (int r = 0; r < 8; ++r) {
                    p[r] = __builtin_amdgcn_exp2f(z[8 + r]);
                    lp[r & 1] += p[r];
                }
                unsigned int e0 = pkrtz(p[0], p[1]), e1 = pkrtz(p[2], p[3]);
                unsigned int f0 = pkrtz(p[4], p[5]), f1 = pkrtz(p[6], p[7]);
                plswap(e0, f0); plswap(e1, f1);
                pf[2 * kt + 1] = __builtin_bit_cast(f16x8, (u32x4){e0, e1, f0, f1});
            }
        }

        // O^T += V^T.P^T
        __builtin_amdgcn_s_setprio(1);
#pragma unroll
        for (int dt = 0; dt < 2; ++dt) {
#pragma unroll
            for (int s = 0; s < 4; ++s) {
                const f16x8 av = __builtin_bit_cast(f16x8, *(const us8*)&Vrd[(dt * 32 + m32) * LQA + half * 8 + 16 * s]);
                O[dt] = __builtin_amdgcn_mfma_f32_32x32x16_f16(av, pf[s], O[dt], 0, 0, 0);
            }
        }
        __builtin_amdgcn_s_setprio(0);

        __syncthreads();   // the chunk's single barrier
    }

    const float lsum = lp[0] + lp[1];
    const float l2 = lsum + __shfl_xor(lsum, 32);   // full row-sum for this key-half
    const int sq = q0 + w * 32 + m32;
    const size_t prow = ((size_t)bh * SLEN + sq) * HD;

    if (FIRST) {
        // dump unnormalized partials (exact combine: bare-exp2 sums add)
#pragma unroll
        for (int dt = 0; dt < 2; ++dt) {
#pragma unroll
            for (int g = 0; g < 4; ++g) {
                const f32x4 o4 = {O[dt][g * 4], O[dt][g * 4 + 1], O[dt][g * 4 + 2], O[dt][g * 4 + 3]};
                *(f32x4*)&Opart[prow + dt * 32 + 8 * g + 4 * half] = o4;
            }
        }
        if (half == 0) lpart[(size_t)bh * SLEN + sq] = l2;
    } else {
        const float lo = lpart[(size_t)bh * SLEN + sq];
        const float rl = 1.0f / (l2 + lo);
        const size_t rowbase = (size_t)(b * SLEN + sq) * DMODEL + h * HD;
#pragma unroll
        for (int dt = 0; dt < 2; ++dt) {
#pragma unroll
            for (int g = 0; g < 4; ++g) {
                const f32x4 part = *(const f32x4*)&Opart[prow + dt * 32 + 8 * g + 4 * half];
                us4 o4;
#pragma unroll
                for (int r2 = 0; r2 < 4; ++r2)
                    o4[r2] = f16bits((O[dt][g * 4 + r2] + part[r2]) * rl);
                *(us4*)&vals[rowbase + dt * 32 + 8 * g + 4 * half] = o4;
            }
        }
    }
#undef LOADKV
}

// ---------------- launch ----------------
extern "C" void kernel_launch(void* const* d_in, const int* in_sizes, int n_in,
                              void* d_out, int out_size, void* d_ws, size_t ws_size,
                              hipStream_t stream) {
    const float* x     = (const float*)d_in[0];
    const float* w_qkv = (const float*)d_in[1];
    const float* b_qkv = (const float*)d_in[2];
    const float* w_o   = (const float*)d_in[3];
    const float* b_o   = (const float*)d_in[4];
    float* out = (float*)d_out;

    const int M   = BATCH * SLEN;        // 4096
    const int XN  = M * DIN;             // 4,194,304
    const int WQN = E3 * DIN;            // 3,145,728
    const int WON = DMODEL * DMODEL;     // 1,048,576
    const size_t QKVN = (size_t)BATCH * SLEN * E3;

    us* qkvh = (us*)d_ws;                // fp16 qkv [QKVN]
    us* xh   = qkvh + QKVN;              // fp16 x [XN], reused for vals
    us* wq   = xh + XN;                  // fp16 w_qkv [WQN]
    us* wo   = wq + WQN;                 // fp16 w_o [WON]
    float* Opart = (float*)(wo + WON);   // f32 attn partial O [32*2048*64]
    float* lpart = Opart + (size_t)BATCH * NHEAD * SLEN * HD;  // f32 [65536]

    // 1) fp32 -> fp16 conversions, one launch
    cvt3_f16<<<dim3((XN + WQN + WON) / 2048), 256, 0, stream>>>(
        x, xh, XN, w_qkv, wq, WQN, w_o, wo);

    // 2) qkv = x @ w_qkv^T + b_qkv -> fp16 (Q cols pre-scaled by QSCALE)
    gemm256_f16<true><<<dim3(E3 / 256, M / 256), 512, 0, stream>>>(
        xh, wq, b_qkv, qkvh, M, E3, DIN);

    // 3) attention in two key-half dispatches (4 blocks/CU each; partial
    //    combine through f32 workspace -- exact for bare-exp2 softmax)
    us* vals = xh;
    attn_half<true><<<dim3((SLEN / ABQ) * BATCH * NHEAD), 256, 0, stream>>>(
        qkvh, vals, Opart, lpart, 0);
    attn_half<false><<<dim3((SLEN / ABQ) * BATCH * NHEAD), 256, 0, stream>>>(
        qkvh, vals, Opart, lpart, CHN);

    // 4) out = vals @ w_o^T + b_o -> fp32; 128x128 tiles: 256 blocks
    gemm_db<128, false><<<dim3(DMODEL / 128, M / 128), 256, 0, stream>>>(
        vals, wo, b_o, out, M, DMODEL, DMODEL);
}